// Round 1
// 476.836 us; speedup vs baseline: 1.0996x; 1.0996x over previous
//
#include <hip/hip_runtime.h>

typedef unsigned short u16;
typedef __attribute__((ext_vector_type(4))) unsigned short u16x4;
typedef __attribute__((ext_vector_type(8))) unsigned short u16x8;
typedef __attribute__((ext_vector_type(8))) short s16x8;
typedef __attribute__((ext_vector_type(4))) float f32x4;

__device__ __forceinline__ float bf2f(u16 u){
  union { unsigned int i; float f; } v; v.i = ((unsigned int)u) << 16; return v.f;
}
__device__ __forceinline__ u16 f2bf(float f){
  union { float f; unsigned int i; } v; v.f = f;
  unsigned int r = v.i + 0x7fffu + ((v.i >> 16) & 1u);   // round-nearest-even
  return (u16)(r >> 16);
}

// ---------------------------------------------------------------------------
// Weight prep: fp32 [COUT][CIN][5] -> bf16 [COUT][k = s*CIN + c]
// ---------------------------------------------------------------------------
__global__ __launch_bounds__(256) void prep_w(
    const float* __restrict__ src, u16* __restrict__ dst, int cout, int cin)
{
  const int n = cout * cin * 5;
  const int i = blockIdx.x * 256 + threadIdx.x;
  if (i >= n) return;
  const int o   = i / (cin * 5);
  const int rem = i - o * cin * 5;
  const int s   = rem / cin;
  const int c   = rem - s * cin;
  dst[i] = f2bf(src[(o * cin + c) * 5 + s]);
}

// ---------------------------------------------------------------------------
// K0: transpose fe [B,64,E] (fp32) -> feT [B,E,64] (bf16)
// ---------------------------------------------------------------------------
__global__ __launch_bounds__(256) void transpose64(
    const float* __restrict__ x, u16* __restrict__ xT, int E)
{
  __shared__ u16 tile[64][66];
  const int b   = blockIdx.z;
  const int e0  = blockIdx.x * 64;
  const int col = threadIdx.x & 63;
  const int r   = threadIdx.x >> 6;
  const int e   = e0 + col;
  #pragma unroll
  for (int k = 0; k < 16; k++) {
    const int c = r * 16 + k;
    float v = 0.f;
    if (e < E) v = x[((size_t)b * 64 + c) * (size_t)E + e];
    tile[c][col] = f2bf(v);
  }
  __syncthreads();
  const int e_l  = threadIdx.x >> 2;
  const int part = threadIdx.x & 3;
  const int eg   = e0 + e_l;
  if (eg < E) {
    u16* dst = xT + ((size_t)b * E + eg) * 64 + part * 16;
    #pragma unroll
    for (int h = 0; h < 2; h++) {
      u16x8 v;
      #pragma unroll
      for (int cc = 0; cc < 8; cc++) v[cc] = tile[part * 16 + h * 8 + cc][e_l];
      *(u16x8*)(dst + h * 8) = v;
    }
  }
}

// ---------------------------------------------------------------------------
// Conv: y[b,o,e] = sum_k W[o,k] * F[k,e] + bias[o], k = s*CIN + c
// xT: [B,E,CIN] bf16, gidx: [B,E,4] int32, W: [128][5*CIN] bf16 (prep_w order),
// bias: [128] fp32, y: [B,128,E] fp32.
// Also emits per-block per-channel partial (sum, sumsq) of y for instance norm.
// One block = 32 edges, all 128 output channels. 256 thr = 4 waves.
// Staging: ALL raw gather loads hoisted to registers first (latency overlap),
// features built per 8-channel chunk, stored with ds_write_b128 (s-major LDS).
// ---------------------------------------------------------------------------
template <int CIN>
__global__ __launch_bounds__(256, (CIN == 64 ? 4 : 3)) void conv_mfma(
    const u16* __restrict__ xT, const int* __restrict__ gidx,
    const u16* __restrict__ W, const float* __restrict__ bias,
    float* __restrict__ y, float2* __restrict__ partials, int E, int nbx)
{
  constexpr int KK  = CIN * 5;
  constexpr int LDC = CIN + 8;              // u16 units; rows stay 16B aligned,
                                            // stride%32dw==4 -> conflict-free
  constexpr int NV  = CIN / 64;             // 8-ch chunks per thread per row
  __shared__ __align__(16) u16 F[5 * 32 * LDC];   // [s][edge][c]

  const int b  = blockIdx.z;
  const int bx = blockIdx.x;
  const int t  = threadIdx.x;
  const int e_l = t >> 3;                   // 0..31
  const int sub = t & 7;                    // 0..7
  const size_t e_raw = (size_t)bx * 32 + e_l;
  const int e = (int)(e_raw < (size_t)E ? e_raw : (size_t)(E - 1));

  int rows[5];
  {
    const int4 g = *(const int4*)(gidx + ((size_t)b * E + e) * 4);
    rows[0] = e; rows[1] = g.x; rows[2] = g.y; rows[3] = g.z; rows[4] = g.w;
  }
  const u16* base = xT + (size_t)b * E * CIN;

  // --- issue ALL gather loads before any use (max in-flight vmem) ---
  u16x8 raw[5][NV];
  #pragma unroll
  for (int j = 0; j < 5; j++) {
    const u16* rp = base + (size_t)rows[j] * CIN + sub * 8;
    #pragma unroll
    for (int v = 0; v < NV; v++)
      raw[j][v] = *(const u16x8*)(rp + v * 64);
  }

  // --- build symmetric features, vector LDS stores ---
  #pragma unroll
  for (int v = 0; v < NV; v++) {
    const int c0 = sub * 8 + v * 64;
    *(u16x8*)&F[(0 * 32 + e_l) * LDC + c0] = raw[0][v];   // self: raw bf16
    u16x8 o1, o2, o3, o4;
    #pragma unroll
    for (int c = 0; c < 8; c++) {
      const float a1 = bf2f(raw[1][v][c]), a2 = bf2f(raw[2][v][c]);
      const float a3 = bf2f(raw[3][v][c]), a4 = bf2f(raw[4][v][c]);
      o1[c] = f2bf(a1 + a3);
      o2[c] = f2bf(a2 + a4);
      o3[c] = f2bf(fabsf(a1 - a3));
      o4[c] = f2bf(fabsf(a2 - a4));
    }
    *(u16x8*)&F[(1 * 32 + e_l) * LDC + c0] = o1;
    *(u16x8*)&F[(2 * 32 + e_l) * LDC + c0] = o2;
    *(u16x8*)&F[(3 * 32 + e_l) * LDC + c0] = o3;
    *(u16x8*)&F[(4 * 32 + e_l) * LDC + c0] = o4;
  }
  __syncthreads();

  // --- MFMA: wave wv covers out rows [wv*32, wv*32+32), 2 n-tiles of 16 ---
  const int lane = t & 63, wv = t >> 6;
  const int lr = lane & 15, quad = lane >> 4;
  f32x4 acc[2][2] = {{{0.f,0.f,0.f,0.f},{0.f,0.f,0.f,0.f}},
                     {{0.f,0.f,0.f,0.f},{0.f,0.f,0.f,0.f}}};
  #pragma unroll
  for (int kt = 0; kt < KK / 32; kt++) {
    const int s  = (kt * 32) / CIN;         // compile-time after unroll
    const int cb = (kt * 32) % CIN;
    const int ko = kt * 32 + quad * 8;
    s16x8 a0 = *(const s16x8*)(W + (size_t)(wv * 32 + lr) * KK + ko);
    s16x8 a1 = *(const s16x8*)(W + (size_t)(wv * 32 + 16 + lr) * KK + ko);
    s16x8 b0 = *(const s16x8*)&F[(s * 32 + lr) * LDC + cb + quad * 8];
    s16x8 b1 = *(const s16x8*)&F[(s * 32 + 16 + lr) * LDC + cb + quad * 8];
    acc[0][0] = __builtin_amdgcn_mfma_f32_16x16x32_bf16(a0, b0, acc[0][0], 0, 0, 0);
    acc[0][1] = __builtin_amdgcn_mfma_f32_16x16x32_bf16(a0, b1, acc[0][1], 0, 0, 0);
    acc[1][0] = __builtin_amdgcn_mfma_f32_16x16x32_bf16(a1, b0, acc[1][0], 0, 0, 0);
    acc[1][1] = __builtin_amdgcn_mfma_f32_16x16x32_bf16(a1, b1, acc[1][1], 0, 0, 0);
  }

  // --- epilogue: D[row=quad*4+r][col=lr]; store y, emit (sum,sumsq) partials ---
  const size_t ybase = (size_t)b * 128;
  #pragma unroll
  for (int i = 0; i < 2; i++) {
    const int m0 = wv * 32 + i * 16 + quad * 4;
    const float4 bs = *(const float4*)(bias + m0);
    #pragma unroll
    for (int r = 0; r < 4; r++) {
      const int m = m0 + r;
      const float bv = ((const float*)&bs)[r];
      float s = 0.f, s2 = 0.f;
      #pragma unroll
      for (int j = 0; j < 2; j++) {
        const size_t eg = (size_t)bx * 32 + j * 16 + lr;
        if (eg < (size_t)E) {
          const float v = acc[i][j][r] + bv;
          y[(ybase + m) * E + eg] = v;
          s += v; s2 += v * v;
        }
      }
      // reduce over the 16 lr lanes (stays inside the quad group)
      #pragma unroll
      for (int mk = 1; mk < 16; mk <<= 1) {
        s  += __shfl_xor(s,  mk);
        s2 += __shfl_xor(s2, mk);
      }
      if (lr == 0)
        partials[(size_t)(b * 128 + m) * nbx + bx] = make_float2(s, s2);
    }
  }
}

// ---------------------------------------------------------------------------
// Reduce per-block partials -> (mean, rsqrt(var+eps)) per (b, o) row
// ---------------------------------------------------------------------------
__global__ __launch_bounds__(256) void stats_finalize(
    const float2* __restrict__ partials, float2* __restrict__ stats,
    int nbx, int E)
{
  const int row = blockIdx.x;
  const float2* p = partials + (size_t)row * nbx;
  float s = 0.f, s2 = 0.f;
  for (int i = threadIdx.x; i < nbx; i += 256) {
    const float2 v = p[i];
    s += v.x; s2 += v.y;
  }
  #pragma unroll
  for (int off = 32; off > 0; off >>= 1) {
    s  += __shfl_down(s, off);
    s2 += __shfl_down(s2, off);
  }
  __shared__ float rs[4], rs2[4];
  const int wv = threadIdx.x >> 6;
  if ((threadIdx.x & 63) == 0) { rs[wv] = s; rs2[wv] = s2; }
  __syncthreads();
  if (threadIdx.x == 0) {
    s  = rs[0] + rs[1] + rs[2] + rs[3];
    s2 = rs2[0] + rs2[1] + rs2[2] + rs2[3];
    const float mean = s / E;
    const float var  = s2 / E - mean * mean;
    stats[row] = make_float2(mean, rsqrtf(var + 1e-5f));
  }
}

// ---------------------------------------------------------------------------
// Normalize + relu; write x1n [B,128,E] bf16 and transposed x1T [B,E,128] bf16
// ---------------------------------------------------------------------------
__global__ __launch_bounds__(256) void norm_relu_tr(
    const float* __restrict__ y, const float2* __restrict__ stats,
    u16* __restrict__ xn, u16* __restrict__ xT, int E)
{
  __shared__ u16 tile[32][66];
  const int b  = blockIdx.z;
  const int o0 = blockIdx.y * 32;
  const int e0 = blockIdx.x * 64;
  const int col = threadIdx.x & 63;
  const int r   = threadIdx.x >> 6;
  const int e   = e0 + col;
  #pragma unroll
  for (int k = 0; k < 8; k++) {
    const int ol = r * 8 + k;
    const int o  = o0 + ol;
    const float2 st = stats[b * 128 + o];
    float v = 0.f;
    if (e < E) v = y[((size_t)b * 128 + o) * E + e];
    float xv = (v - st.x) * st.y;
    if (xv < 0.f) xv = 0.f;
    const u16 u = f2bf(xv);
    if (e < E) xn[((size_t)b * 128 + o) * E + e] = u;
    tile[ol][col] = u;
  }
  __syncthreads();
  const int e_l  = threadIdx.x >> 2;
  const int part = threadIdx.x & 3;
  const int eg   = e0 + e_l;
  if (eg < E) {
    u16x8 v;
    #pragma unroll
    for (int cc = 0; cc < 8; cc++) v[cc] = tile[part * 8 + cc][e_l];
    *(u16x8*)(xT + ((size_t)b * E + eg) * 128 + o0 + part * 8) = v;
  }
}

// ---------------------------------------------------------------------------
// Final: out = relu( (y2 - m)*rstd + x1n ), fp32 — float4 vectorized
// ---------------------------------------------------------------------------
__global__ __launch_bounds__(256) void final_k(
    const float* __restrict__ y, const float2* __restrict__ stats,
    const u16* __restrict__ xn, float* __restrict__ out, int E)
{
  const int b = blockIdx.z, o = blockIdx.y;
  const int e0 = (blockIdx.x * 256 + threadIdx.x) * 4;
  if (e0 >= E) return;
  const float2 st = stats[b * 128 + o];
  const size_t base = ((size_t)b * 128 + o) * E;
  if (e0 + 4 <= E) {
    const float4 v = *(const float4*)(y + base + e0);
    const u16x4 xv = *(const u16x4*)(xn + base + e0);
    float4 r;
    r.x = (v.x - st.x) * st.y + bf2f(xv[0]);
    r.y = (v.y - st.x) * st.y + bf2f(xv[1]);
    r.z = (v.z - st.x) * st.y + bf2f(xv[2]);
    r.w = (v.w - st.x) * st.y + bf2f(xv[3]);
    r.x = r.x < 0.f ? 0.f : r.x;
    r.y = r.y < 0.f ? 0.f : r.y;
    r.z = r.z < 0.f ? 0.f : r.z;
    r.w = r.w < 0.f ? 0.f : r.w;
    *(float4*)(out + base + e0) = r;
  } else {
    for (int ee = e0; ee < E; ee++) {
      float v = (y[base + ee] - st.x) * st.y + bf2f(xn[base + ee]);
      out[base + ee] = v < 0.f ? 0.f : v;
    }
  }
}

// ---------------------------------------------------------------------------
extern "C" void kernel_launch(void* const* d_in, const int* in_sizes, int n_in,
                              void* d_out, int out_size, void* d_ws, size_t ws_size,
                              hipStream_t stream)
{
  const float* fe  = (const float*)d_in[0];
  const int*   gmm = (const int*)d_in[1];
  const float* w1  = (const float*)d_in[2];
  const float* b1  = (const float*)d_in[3];
  const float* w2  = (const float*)d_in[4];
  const float* b2  = (const float*)d_in[5];
  float* out = (float*)d_out;

  const int B = 2, CIN = 64, COUT = 128;
  const int E = in_sizes[0] / (B * CIN);   // 100000
  const int nbx = (E + 31) / 32;

  // workspace layout (feT aliased with x1n: feT dead before x1n written)
  char* p = (char*)d_ws;
  auto alloc = [&](size_t bytes) -> char* {
    char* q = p; p += (bytes + 255) & ~(size_t)255; return q;
  };
  const size_t feT_b = (size_t)B * E * CIN * 2;
  const size_t x1n_b = (size_t)B * COUT * E * 2;
  char* regA = alloc(x1n_b > feT_b ? x1n_b : feT_b);
  u16*   feT = (u16*)regA;
  u16*   x1n = (u16*)regA;
  u16*   x1T = (u16*)alloc((size_t)B * E * COUT * 2);
  float* y   = (float*)alloc((size_t)B * COUT * E * 4);
  float2* stats = (float2*)alloc((size_t)B * COUT * sizeof(float2));
  u16* w1b = (u16*)alloc((size_t)COUT * CIN * 5 * 2);
  u16* w2b = (u16*)alloc((size_t)COUT * COUT * 5 * 2);
  // partials scratch lives in d_out: dead by the time final_k writes out
  float2* partials = (float2*)d_out;   // B*COUT*nbx*8B = 6.4 MB << out_size

  const int n_w1 = COUT * CIN * 5, n_w2 = COUT * COUT * 5;
  prep_w <<<dim3((n_w1 + 255) / 256), 256, 0, stream>>>(w1, w1b, COUT, CIN);
  prep_w <<<dim3((n_w2 + 255) / 256), 256, 0, stream>>>(w2, w2b, COUT, COUT);

  transpose64 <<<dim3((E + 63) / 64, 1, B), 256, 0, stream>>>(fe, feT, E);
  conv_mfma<64> <<<dim3(nbx, 1, B), 256, 0, stream>>>(feT, gmm, w1b, b1, y, partials, E, nbx);
  stats_finalize <<<dim3(B * COUT), 256, 0, stream>>>(partials, stats, nbx, E);
  norm_relu_tr <<<dim3((E + 63) / 64, COUT / 32, B), 256, 0, stream>>>(y, stats, x1n, x1T, E);
  conv_mfma<128> <<<dim3(nbx, 1, B), 256, 0, stream>>>(x1T, gmm, w2b, b2, y, partials, E, nbx);
  stats_finalize <<<dim3(B * COUT), 256, 0, stream>>>(partials, stats, nbx, E);
  final_k <<<dim3(((E + 3) / 4 + 255) / 256, COUT, B), 256, 0, stream>>>(y, stats, x1n, out, E);
}

// Round 2
// 446.299 us; speedup vs baseline: 1.1748x; 1.0684x over previous
//
#include <hip/hip_runtime.h>

typedef unsigned short u16;
typedef __attribute__((ext_vector_type(4))) unsigned short u16x4;
typedef __attribute__((ext_vector_type(8))) unsigned short u16x8;
typedef __attribute__((ext_vector_type(8))) short s16x8;
typedef __attribute__((ext_vector_type(4))) float f32x4;

__device__ __forceinline__ float bf2f(u16 u){
  union { unsigned int i; float f; } v; v.i = ((unsigned int)u) << 16; return v.f;
}
__device__ __forceinline__ u16 f2bf(float f){
  union { float f; unsigned int i; } v; v.f = f;
  unsigned int r = v.i + 0x7fffu + ((v.i >> 16) & 1u);   // round-nearest-even
  return (u16)(r >> 16);
}

// ---------------------------------------------------------------------------
// Weight prep: fp32 [COUT][CIN][5] -> bf16 [COUT][k = s*CIN + c]
// ---------------------------------------------------------------------------
__global__ __launch_bounds__(256) void prep_w(
    const float* __restrict__ src, u16* __restrict__ dst, int cout, int cin)
{
  const int n = cout * cin * 5;
  const int i = blockIdx.x * 256 + threadIdx.x;
  if (i >= n) return;
  const int o   = i / (cin * 5);
  const int rem = i - o * cin * 5;
  const int s   = rem / cin;
  const int c   = rem - s * cin;
  dst[i] = f2bf(src[(o * cin + c) * 5 + s]);
}

// ---------------------------------------------------------------------------
// K0: transpose fe [B,64,E] (fp32) -> feT [B,E,64] (bf16)
// ---------------------------------------------------------------------------
__global__ __launch_bounds__(256) void transpose64(
    const float* __restrict__ x, u16* __restrict__ xT, int E)
{
  __shared__ u16 tile[64][66];
  const int b   = blockIdx.z;
  const int e0  = blockIdx.x * 64;
  const int col = threadIdx.x & 63;
  const int r   = threadIdx.x >> 6;
  const int e   = e0 + col;
  #pragma unroll
  for (int k = 0; k < 16; k++) {
    const int c = r * 16 + k;
    float v = 0.f;
    if (e < E) v = x[((size_t)b * 64 + c) * (size_t)E + e];
    tile[c][col] = f2bf(v);
  }
  __syncthreads();
  const int e_l  = threadIdx.x >> 2;
  const int part = threadIdx.x & 3;
  const int eg   = e0 + e_l;
  if (eg < E) {
    u16* dst = xT + ((size_t)b * E + eg) * 64 + part * 16;
    #pragma unroll
    for (int h = 0; h < 2; h++) {
      u16x8 v;
      #pragma unroll
      for (int cc = 0; cc < 8; cc++) v[cc] = tile[part * 16 + h * 8 + cc][e_l];
      *(u16x8*)(dst + h * 8) = v;
    }
  }
}

// ---------------------------------------------------------------------------
// Conv: y[b,o,e] = sum_k W[o,k] * F[k,e] + bias[o], k = s*CIN + c
// 512 threads = 8 waves. EPB edges per block (64 for CIN=64, 32 for CIN=128),
// 3 blocks/CU = 24 waves/CU (latency hiding for the random gathers).
// All 5 gather loads force-issued before any use via sched_barrier(0).
// Each wave owns a 16-row m-tile; n-tiles NT = EPB/16.
// Emits per-block per-channel (sum, sumsq) partials for fused instance norm.
// ---------------------------------------------------------------------------
template <int CIN>
__global__ __launch_bounds__(512, 6) void conv_mfma(
    const u16* __restrict__ xT, const int* __restrict__ gidx,
    const u16* __restrict__ W, const float* __restrict__ bias,
    float* __restrict__ y, float2* __restrict__ partials, int E, int nbx)
{
  constexpr int EPB = (CIN == 64) ? 64 : 32;   // edges per block
  constexpr int SUB = 512 / EPB;               // sub-threads per edge (8 / 16)
  constexpr int KK  = CIN * 5;
  constexpr int LDC = CIN + 8;                 // row stride (u16), 16B-aligned
  constexpr int NT  = EPB / 16;                // n-tiles per wave (4 / 2)
  __shared__ __align__(16) u16 F[5 * EPB * LDC];   // [s][edge][c]

  const int b  = blockIdx.z;
  const int bx = blockIdx.x;
  const int t  = threadIdx.x;
  const int e_l = t / SUB;                     // 0..EPB-1
  const int sub = t % SUB;                     // 0..SUB-1, 8 channels each
  const size_t e_raw = (size_t)bx * EPB + e_l;
  const int e = (int)(e_raw < (size_t)E ? e_raw : (size_t)(E - 1));

  int rows[5];
  {
    const int4 g = *(const int4*)(gidx + ((size_t)b * E + e) * 4);
    rows[0] = e; rows[1] = g.x; rows[2] = g.y; rows[3] = g.z; rows[4] = g.w;
  }
  const u16* base = xT + (size_t)b * E * CIN + sub * 8;

  // --- force-issue ALL 5 gather loads before any conversion ---
  u16x8 raw[5];
  #pragma unroll
  for (int j = 0; j < 5; j++)
    raw[j] = *(const u16x8*)(base + (size_t)rows[j] * CIN);
  __builtin_amdgcn_sched_barrier(0);

  // --- build symmetric features, vector LDS stores ---
  {
    const int c0 = sub * 8;
    *(u16x8*)&F[(0 * EPB + e_l) * LDC + c0] = raw[0];   // self: raw bf16
    u16x8 o1, o2, o3, o4;
    #pragma unroll
    for (int c = 0; c < 8; c++) {
      const float a1 = bf2f(raw[1][c]), a2 = bf2f(raw[2][c]);
      const float a3 = bf2f(raw[3][c]), a4 = bf2f(raw[4][c]);
      o1[c] = f2bf(a1 + a3);
      o2[c] = f2bf(a2 + a4);
      o3[c] = f2bf(fabsf(a1 - a3));
      o4[c] = f2bf(fabsf(a2 - a4));
    }
    *(u16x8*)&F[(1 * EPB + e_l) * LDC + c0] = o1;
    *(u16x8*)&F[(2 * EPB + e_l) * LDC + c0] = o2;
    *(u16x8*)&F[(3 * EPB + e_l) * LDC + c0] = o3;
    *(u16x8*)&F[(4 * EPB + e_l) * LDC + c0] = o4;
  }
  __syncthreads();

  // --- MFMA: wave wv owns m-rows [wv*16, wv*16+16), NT n-tiles of 16 ---
  const int lane = t & 63, wv = t >> 6;        // wv 0..7
  const int lr = lane & 15, quad = lane >> 4;
  f32x4 acc[NT];
  #pragma unroll
  for (int j = 0; j < NT; j++) acc[j] = (f32x4){0.f, 0.f, 0.f, 0.f};
  #pragma unroll
  for (int kt = 0; kt < KK / 32; kt++) {
    const int s  = (kt * 32) / CIN;            // compile-time after unroll
    const int cb = (kt * 32) % CIN;
    const int ko = kt * 32 + quad * 8;
    const s16x8 a0 = *(const s16x8*)(W + (size_t)(wv * 16 + lr) * KK + ko);
    #pragma unroll
    for (int j = 0; j < NT; j++) {
      const s16x8 bj = *(const s16x8*)&F[(s * EPB + j * 16 + lr) * LDC + cb + quad * 8];
      acc[j] = __builtin_amdgcn_mfma_f32_16x16x32_bf16(a0, bj, acc[j], 0, 0, 0);
    }
  }

  // --- epilogue: D[row=quad*4+r][col=lr]; store y, emit (sum,sumsq) partials ---
  const size_t ybase = (size_t)b * 128;
  const int m0 = wv * 16 + quad * 4;
  const float4 bs = *(const float4*)(bias + m0);
  #pragma unroll
  for (int r = 0; r < 4; r++) {
    const int m = m0 + r;
    const float bv = ((const float*)&bs)[r];
    float s = 0.f, s2 = 0.f;
    #pragma unroll
    for (int j = 0; j < NT; j++) {
      const size_t eg = (size_t)bx * EPB + j * 16 + lr;
      if (eg < (size_t)E) {
        const float v = acc[j][r] + bv;
        y[(ybase + m) * E + eg] = v;
        s += v; s2 += v * v;
      }
    }
    // reduce over the 16 lr lanes (stays inside the quad group)
    #pragma unroll
    for (int mk = 1; mk < 16; mk <<= 1) {
      s  += __shfl_xor(s,  mk);
      s2 += __shfl_xor(s2, mk);
    }
    if (lr == 0)
      partials[(size_t)(b * 128 + m) * nbx + bx] = make_float2(s, s2);
  }
}

// ---------------------------------------------------------------------------
// Reduce per-block partials -> (mean, rsqrt(var+eps)) per (b, o) row
// ---------------------------------------------------------------------------
__global__ __launch_bounds__(256) void stats_finalize(
    const float2* __restrict__ partials, float2* __restrict__ stats,
    int nbx, int E)
{
  const int row = blockIdx.x;
  const float2* p = partials + (size_t)row * nbx;
  float s = 0.f, s2 = 0.f;
  for (int i = threadIdx.x; i < nbx; i += 256) {
    const float2 v = p[i];
    s += v.x; s2 += v.y;
  }
  #pragma unroll
  for (int off = 32; off > 0; off >>= 1) {
    s  += __shfl_down(s, off);
    s2 += __shfl_down(s2, off);
  }
  __shared__ float rs[4], rs2[4];
  const int wv = threadIdx.x >> 6;
  if ((threadIdx.x & 63) == 0) { rs[wv] = s; rs2[wv] = s2; }
  __syncthreads();
  if (threadIdx.x == 0) {
    s  = rs[0] + rs[1] + rs[2] + rs[3];
    s2 = rs2[0] + rs2[1] + rs2[2] + rs2[3];
    const float mean = s / E;
    const float var  = s2 / E - mean * mean;
    stats[row] = make_float2(mean, rsqrtf(var + 1e-5f));
  }
}

// ---------------------------------------------------------------------------
// Normalize + relu; write x1n [B,128,E] bf16 and transposed x1T [B,E,128] bf16
// ---------------------------------------------------------------------------
__global__ __launch_bounds__(256) void norm_relu_tr(
    const float* __restrict__ y, const float2* __restrict__ stats,
    u16* __restrict__ xn, u16* __restrict__ xT, int E)
{
  __shared__ u16 tile[32][66];
  const int b  = blockIdx.z;
  const int o0 = blockIdx.y * 32;
  const int e0 = blockIdx.x * 64;
  const int col = threadIdx.x & 63;
  const int r   = threadIdx.x >> 6;
  const int e   = e0 + col;
  #pragma unroll
  for (int k = 0; k < 8; k++) {
    const int ol = r * 8 + k;
    const int o  = o0 + ol;
    const float2 st = stats[b * 128 + o];
    float v = 0.f;
    if (e < E) v = y[((size_t)b * 128 + o) * E + e];
    float xv = (v - st.x) * st.y;
    if (xv < 0.f) xv = 0.f;
    const u16 u = f2bf(xv);
    if (e < E) xn[((size_t)b * 128 + o) * E + e] = u;
    tile[ol][col] = u;
  }
  __syncthreads();
  const int e_l  = threadIdx.x >> 2;
  const int part = threadIdx.x & 3;
  const int eg   = e0 + e_l;
  if (eg < E) {
    u16x8 v;
    #pragma unroll
    for (int cc = 0; cc < 8; cc++) v[cc] = tile[part * 8 + cc][e_l];
    *(u16x8*)(xT + ((size_t)b * E + eg) * 128 + o0 + part * 8) = v;
  }
}

// ---------------------------------------------------------------------------
// Final: out = relu( (y2 - m)*rstd + x1n ), fp32 — float4 vectorized
// ---------------------------------------------------------------------------
__global__ __launch_bounds__(256) void final_k(
    const float* __restrict__ y, const float2* __restrict__ stats,
    const u16* __restrict__ xn, float* __restrict__ out, int E)
{
  const int b = blockIdx.z, o = blockIdx.y;
  const int e0 = (blockIdx.x * 256 + threadIdx.x) * 4;
  if (e0 >= E) return;
  const float2 st = stats[b * 128 + o];
  const size_t base = ((size_t)b * 128 + o) * E;
  if (e0 + 4 <= E) {
    const float4 v = *(const float4*)(y + base + e0);
    const u16x4 xv = *(const u16x4*)(xn + base + e0);
    float4 r;
    r.x = (v.x - st.x) * st.y + bf2f(xv[0]);
    r.y = (v.y - st.x) * st.y + bf2f(xv[1]);
    r.z = (v.z - st.x) * st.y + bf2f(xv[2]);
    r.w = (v.w - st.x) * st.y + bf2f(xv[3]);
    r.x = r.x < 0.f ? 0.f : r.x;
    r.y = r.y < 0.f ? 0.f : r.y;
    r.z = r.z < 0.f ? 0.f : r.z;
    r.w = r.w < 0.f ? 0.f : r.w;
    *(float4*)(out + base + e0) = r;
  } else {
    for (int ee = e0; ee < E; ee++) {
      float v = (y[base + ee] - st.x) * st.y + bf2f(xn[base + ee]);
      out[base + ee] = v < 0.f ? 0.f : v;
    }
  }
}

// ---------------------------------------------------------------------------
extern "C" void kernel_launch(void* const* d_in, const int* in_sizes, int n_in,
                              void* d_out, int out_size, void* d_ws, size_t ws_size,
                              hipStream_t stream)
{
  const float* fe  = (const float*)d_in[0];
  const int*   gmm = (const int*)d_in[1];
  const float* w1  = (const float*)d_in[2];
  const float* b1  = (const float*)d_in[3];
  const float* w2  = (const float*)d_in[4];
  const float* b2  = (const float*)d_in[5];
  float* out = (float*)d_out;

  const int B = 2, CIN = 64, COUT = 128;
  const int E = in_sizes[0] / (B * CIN);   // 100000
  const int nbx1 = (E + 63) / 64;          // conv<64>: EPB=64
  const int nbx2 = (E + 31) / 32;          // conv<128>: EPB=32

  // workspace layout (feT aliased with x1n: feT dead before x1n written)
  char* p = (char*)d_ws;
  auto alloc = [&](size_t bytes) -> char* {
    char* q = p; p += (bytes + 255) & ~(size_t)255; return q;
  };
  const size_t feT_b = (size_t)B * E * CIN * 2;
  const size_t x1n_b = (size_t)B * COUT * E * 2;
  char* regA = alloc(x1n_b > feT_b ? x1n_b : feT_b);
  u16*   feT = (u16*)regA;
  u16*   x1n = (u16*)regA;
  u16*   x1T = (u16*)alloc((size_t)B * E * COUT * 2);
  float* y   = (float*)alloc((size_t)B * COUT * E * 4);
  float2* stats = (float2*)alloc((size_t)B * COUT * sizeof(float2));
  u16* w1b = (u16*)alloc((size_t)COUT * CIN * 5 * 2);
  u16* w2b = (u16*)alloc((size_t)COUT * COUT * 5 * 2);
  // partials scratch lives in d_out: dead by the time final_k writes out
  float2* partials = (float2*)d_out;   // <= 256*nbx2*8B = 6.4 MB << out_size

  const int n_w1 = COUT * CIN * 5, n_w2 = COUT * COUT * 5;
  prep_w <<<dim3((n_w1 + 255) / 256), 256, 0, stream>>>(w1, w1b, COUT, CIN);
  prep_w <<<dim3((n_w2 + 255) / 256), 256, 0, stream>>>(w2, w2b, COUT, COUT);

  transpose64 <<<dim3((E + 63) / 64, 1, B), 256, 0, stream>>>(fe, feT, E);
  conv_mfma<64> <<<dim3(nbx1, 1, B), 512, 0, stream>>>(feT, gmm, w1b, b1, y, partials, E, nbx1);
  stats_finalize <<<dim3(B * COUT), 256, 0, stream>>>(partials, stats, nbx1, E);
  norm_relu_tr <<<dim3((E + 63) / 64, COUT / 32, B), 256, 0, stream>>>(y, stats, x1n, x1T, E);
  conv_mfma<128> <<<dim3(nbx2, 1, B), 512, 0, stream>>>(x1T, gmm, w2b, b2, y, partials, E, nbx2);
  stats_finalize <<<dim3(B * COUT), 256, 0, stream>>>(partials, stats, nbx2, E);
  final_k <<<dim3(((E + 3) / 4 + 255) / 256, COUT, B), 256, 0, stream>>>(y, stats, x1n, out, E);
}

// Round 3
// 422.969 us; speedup vs baseline: 1.2397x; 1.0552x over previous
//
#include <hip/hip_runtime.h>

typedef unsigned short u16;
typedef __attribute__((ext_vector_type(4))) unsigned short u16x4;
typedef __attribute__((ext_vector_type(8))) unsigned short u16x8;
typedef __attribute__((ext_vector_type(8))) short s16x8;
typedef __attribute__((ext_vector_type(4))) float f32x4;

__device__ __forceinline__ float bf2f(u16 u){
  union { unsigned int i; float f; } v; v.i = ((unsigned int)u) << 16; return v.f;
}
__device__ __forceinline__ u16 f2bf(float f){
  union { float f; unsigned int i; } v; v.f = f;
  unsigned int r = v.i + 0x7fffu + ((v.i >> 16) & 1u);   // round-nearest-even
  return (u16)(r >> 16);
}

// ---------------------------------------------------------------------------
// Weight prep: fp32 [COUT][CIN][5] -> bf16 [COUT][k = s*CIN + c]
// ---------------------------------------------------------------------------
__global__ __launch_bounds__(256) void prep_w(
    const float* __restrict__ src, u16* __restrict__ dst, int cout, int cin)
{
  const int n = cout * cin * 5;
  const int i = blockIdx.x * 256 + threadIdx.x;
  if (i >= n) return;
  const int o   = i / (cin * 5);
  const int rem = i - o * cin * 5;
  const int s   = rem / cin;
  const int c   = rem - s * cin;
  dst[i] = f2bf(src[(o * cin + c) * 5 + s]);
}

// ---------------------------------------------------------------------------
// K0: transpose fe [B,64,E] (fp32) -> feT [B,E,64] (bf16)
// ---------------------------------------------------------------------------
__global__ __launch_bounds__(256) void transpose64(
    const float* __restrict__ x, u16* __restrict__ xT, int E)
{
  __shared__ u16 tile[64][66];
  const int b   = blockIdx.z;
  const int e0  = blockIdx.x * 64;
  const int col = threadIdx.x & 63;
  const int r   = threadIdx.x >> 6;
  const int e   = e0 + col;
  #pragma unroll
  for (int k = 0; k < 16; k++) {
    const int c = r * 16 + k;
    float v = 0.f;
    if (e < E) v = x[((size_t)b * 64 + c) * (size_t)E + e];
    tile[c][col] = f2bf(v);
  }
  __syncthreads();
  const int e_l  = threadIdx.x >> 2;
  const int part = threadIdx.x & 3;
  const int eg   = e0 + e_l;
  if (eg < E) {
    u16* dst = xT + ((size_t)b * E + eg) * 64 + part * 16;
    #pragma unroll
    for (int h = 0; h < 2; h++) {
      u16x8 v;
      #pragma unroll
      for (int cc = 0; cc < 8; cc++) v[cc] = tile[part * 16 + h * 8 + cc][e_l];
      *(u16x8*)(dst + h * 8) = v;
    }
  }
}

// ---------------------------------------------------------------------------
// conv1: y1[b,e,o] = sum_k W[o,k]*F[k,e] + bias[o]  (pre-norm, fp32, EDGE-major)
// Swapped-operand MFMA: mfma(F_frag, W_frag) -> D[row=edge][col=channel], so
// the epilogue writes channel-contiguous 64B runs per edge (no LDS transpose).
// 512 thr = 8 waves, EPB=64 edges/block, 3 blocks/CU.
// ---------------------------------------------------------------------------
__global__ __launch_bounds__(512, 6) void conv1_mfma(
    const u16* __restrict__ xT, const int* __restrict__ gidx,
    const u16* __restrict__ W, const float* __restrict__ bias,
    float* __restrict__ y1, float2* __restrict__ partials, int E, int nbx)
{
  constexpr int CIN = 64, EPB = 64, SUB = 8;
  constexpr int KK  = CIN * 5;
  constexpr int LDC = CIN + 8;
  constexpr int NT  = EPB / 16;                // 4
  __shared__ __align__(16) u16 F[5 * EPB * LDC];   // 46080 B

  const int b  = blockIdx.z;
  const int bx = blockIdx.x;
  const int t  = threadIdx.x;
  const int e_l = t / SUB;                     // 0..63
  const int sub = t % SUB;                     // 0..7
  const size_t e_raw = (size_t)bx * EPB + e_l;
  const int e = (int)(e_raw < (size_t)E ? e_raw : (size_t)(E - 1));

  int rows[5];
  {
    const int4 g = *(const int4*)(gidx + ((size_t)b * E + e) * 4);
    rows[0] = e; rows[1] = g.x; rows[2] = g.y; rows[3] = g.z; rows[4] = g.w;
  }
  const u16* base = xT + (size_t)b * E * CIN + sub * 8;

  u16x8 raw[5];
  #pragma unroll
  for (int j = 0; j < 5; j++)
    raw[j] = *(const u16x8*)(base + (size_t)rows[j] * CIN);
  __builtin_amdgcn_sched_barrier(0);

  {
    const int c0 = sub * 8;
    *(u16x8*)&F[(0 * EPB + e_l) * LDC + c0] = raw[0];
    u16x8 o1, o2, o3, o4;
    #pragma unroll
    for (int c = 0; c < 8; c++) {
      const float a1 = bf2f(raw[1][c]), a2 = bf2f(raw[2][c]);
      const float a3 = bf2f(raw[3][c]), a4 = bf2f(raw[4][c]);
      o1[c] = f2bf(a1 + a3);
      o2[c] = f2bf(a2 + a4);
      o3[c] = f2bf(fabsf(a1 - a3));
      o4[c] = f2bf(fabsf(a2 - a4));
    }
    *(u16x8*)&F[(1 * EPB + e_l) * LDC + c0] = o1;
    *(u16x8*)&F[(2 * EPB + e_l) * LDC + c0] = o2;
    *(u16x8*)&F[(3 * EPB + e_l) * LDC + c0] = o3;
    *(u16x8*)&F[(4 * EPB + e_l) * LDC + c0] = o4;
  }
  __syncthreads();

  const int lane = t & 63, wv = t >> 6;
  const int lr = lane & 15, quad = lane >> 4;
  f32x4 acc[NT];
  #pragma unroll
  for (int j = 0; j < NT; j++) acc[j] = (f32x4){0.f, 0.f, 0.f, 0.f};
  #pragma unroll
  for (int kt = 0; kt < KK / 32; kt++) {
    const int s  = (kt * 32) / CIN;
    const int cb = (kt * 32) % CIN;
    const int ko = kt * 32 + quad * 8;
    const s16x8 a0 = *(const s16x8*)(W + (size_t)(wv * 16 + lr) * KK + ko);
    #pragma unroll
    for (int j = 0; j < NT; j++) {
      const s16x8 bj = *(const s16x8*)&F[(s * EPB + j * 16 + lr) * LDC + cb + quad * 8];
      // swapped: D[row=edge][col=channel]
      acc[j] = __builtin_amdgcn_mfma_f32_16x16x32_bf16(bj, a0, acc[j], 0, 0, 0);
    }
  }

  // epilogue: lane holds edges (j*16+quad*4+r), channel = wv*16+lr
  const int ch = wv * 16 + lr;
  const float bv = bias[ch];
  float s = 0.f, s2 = 0.f;
  #pragma unroll
  for (int j = 0; j < NT; j++) {
    #pragma unroll
    for (int r = 0; r < 4; r++) {
      const int el = j * 16 + quad * 4 + r;
      const size_t eg = (size_t)bx * EPB + el;
      if (eg < (size_t)E) {
        const float v = acc[j][r] + bv;
        y1[((size_t)b * E + eg) * 128 + ch] = v;
        s += v; s2 += v * v;
      }
    }
  }
  s  += __shfl_xor(s, 16);  s  += __shfl_xor(s, 32);
  s2 += __shfl_xor(s2, 16); s2 += __shfl_xor(s2, 32);
  if (lane < 16)
    partials[(size_t)(b * 128 + ch) * nbx + bx] = make_float2(s, s2);
}

// ---------------------------------------------------------------------------
// conv2: gathers RAW y1 rows, applies instance-norm+ReLU per channel on the
// fly (stats1), builds symmetric features bf16, MFMA W2 ->
// y2[b,o,e] fp32 channel-major (nontemporal) + partials.
// ---------------------------------------------------------------------------
__global__ __launch_bounds__(512, 6) void conv2_mfma(
    const float* __restrict__ x1, const int* __restrict__ gidx,
    const u16* __restrict__ W, const float* __restrict__ bias,
    const float2* __restrict__ stats1,
    float* __restrict__ y2, float2* __restrict__ partials, int E, int nbx)
{
  constexpr int CIN = 128, EPB = 32, SUB = 16;
  constexpr int KK  = CIN * 5;
  constexpr int LDC = CIN + 8;
  constexpr int NT  = EPB / 16;                // 2
  __shared__ __align__(16) u16 F[5 * EPB * LDC];   // 43520 B
  __shared__ float2 sst[128];

  const int b  = blockIdx.z;
  const int bx = blockIdx.x;
  const int t  = threadIdx.x;
  const int e_l = t / SUB;                     // 0..31
  const int sub = t % SUB;                     // 0..15
  const size_t e_raw = (size_t)bx * EPB + e_l;
  const int e = (int)(e_raw < (size_t)E ? e_raw : (size_t)(E - 1));

  int rows[5];
  {
    const int4 g = *(const int4*)(gidx + ((size_t)b * E + e) * 4);
    rows[0] = e; rows[1] = g.x; rows[2] = g.y; rows[3] = g.z; rows[4] = g.w;
  }
  const float* base = x1 + (size_t)b * E * 128 + sub * 8;

  // force-issue all 5 gather loads (2x float4 each) before any use
  f32x4 raw[5][2];
  #pragma unroll
  for (int j = 0; j < 5; j++) {
    const float* rp = base + (size_t)rows[j] * 128;
    raw[j][0] = *(const f32x4*)rp;
    raw[j][1] = *(const f32x4*)(rp + 4);
  }
  __builtin_amdgcn_sched_barrier(0);

  if (t < 128) sst[t] = stats1[b * 128 + t];
  __syncthreads();

  {
    const int c0 = sub * 8;
    u16x8 o0, o1, o2, o3, o4;
    #pragma unroll
    for (int c = 0; c < 8; c++) {
      const float2 stc = sst[c0 + c];
      float x[5];
      #pragma unroll
      for (int j = 0; j < 5; j++) {
        float v = (c < 4) ? raw[j][0][c] : raw[j][1][c - 4];
        v = (v - stc.x) * stc.y;
        x[j] = v < 0.f ? 0.f : v;
      }
      o0[c] = f2bf(x[0]);
      o1[c] = f2bf(x[1] + x[3]);
      o2[c] = f2bf(x[2] + x[4]);
      o3[c] = f2bf(fabsf(x[1] - x[3]));
      o4[c] = f2bf(fabsf(x[2] - x[4]));
    }
    *(u16x8*)&F[(0 * EPB + e_l) * LDC + c0] = o0;
    *(u16x8*)&F[(1 * EPB + e_l) * LDC + c0] = o1;
    *(u16x8*)&F[(2 * EPB + e_l) * LDC + c0] = o2;
    *(u16x8*)&F[(3 * EPB + e_l) * LDC + c0] = o3;
    *(u16x8*)&F[(4 * EPB + e_l) * LDC + c0] = o4;
  }
  __syncthreads();

  const int lane = t & 63, wv = t >> 6;
  const int lr = lane & 15, quad = lane >> 4;
  f32x4 acc[NT];
  #pragma unroll
  for (int j = 0; j < NT; j++) acc[j] = (f32x4){0.f, 0.f, 0.f, 0.f};
  #pragma unroll
  for (int kt = 0; kt < KK / 32; kt++) {
    const int s  = (kt * 32) / CIN;
    const int cb = (kt * 32) % CIN;
    const int ko = kt * 32 + quad * 8;
    const s16x8 a0 = *(const s16x8*)(W + (size_t)(wv * 16 + lr) * KK + ko);
    #pragma unroll
    for (int j = 0; j < NT; j++) {
      const s16x8 bj = *(const s16x8*)&F[(s * EPB + j * 16 + lr) * LDC + cb + quad * 8];
      acc[j] = __builtin_amdgcn_mfma_f32_16x16x32_bf16(a0, bj, acc[j], 0, 0, 0);
    }
  }

  // epilogue: D[row=channel(quad*4+r)][col=edge(lr)]
  const size_t ybase = (size_t)b * 128;
  const int m0 = wv * 16 + quad * 4;
  const float4 bs = *(const float4*)(bias + m0);
  #pragma unroll
  for (int r = 0; r < 4; r++) {
    const int m = m0 + r;
    const float bv = ((const float*)&bs)[r];
    float s = 0.f, s2 = 0.f;
    #pragma unroll
    for (int j = 0; j < NT; j++) {
      const size_t eg = (size_t)bx * EPB + j * 16 + lr;
      if (eg < (size_t)E) {
        const float v = acc[j][r] + bv;
        __builtin_nontemporal_store(v, &y2[(ybase + m) * E + eg]);
        s += v; s2 += v * v;
      }
    }
    #pragma unroll
    for (int mk = 1; mk < 16; mk <<= 1) {
      s  += __shfl_xor(s,  mk);
      s2 += __shfl_xor(s2, mk);
    }
    if (lr == 0)
      partials[(size_t)(b * 128 + m) * nbx + bx] = make_float2(s, s2);
  }
}

// ---------------------------------------------------------------------------
// Reduce per-block partials -> (mean, rsqrt(var+eps)) per (b, o) row
// ---------------------------------------------------------------------------
__global__ __launch_bounds__(256) void stats_finalize(
    const float2* __restrict__ partials, float2* __restrict__ stats,
    int nbx, int E)
{
  const int row = blockIdx.x;
  const float2* p = partials + (size_t)row * nbx;
  float s = 0.f, s2 = 0.f;
  for (int i = threadIdx.x; i < nbx; i += 256) {
    const float2 v = p[i];
    s += v.x; s2 += v.y;
  }
  #pragma unroll
  for (int off = 32; off > 0; off >>= 1) {
    s  += __shfl_down(s, off);
    s2 += __shfl_down(s2, off);
  }
  __shared__ float rs[4], rs2[4];
  const int wv = threadIdx.x >> 6;
  if ((threadIdx.x & 63) == 0) { rs[wv] = s; rs2[wv] = s2; }
  __syncthreads();
  if (threadIdx.x == 0) {
    s  = rs[0] + rs[1] + rs[2] + rs[3];
    s2 = rs2[0] + rs2[1] + rs2[2] + rs2[3];
    const float mean = s / E;
    const float var  = s2 / E - mean * mean;
    stats[row] = make_float2(mean, rsqrtf(var + 1e-5f));
  }
}

// ---------------------------------------------------------------------------
// Final: out[b,o,e] = relu( (y2-m2)*r2 + relu((y1[e,o]-m1)*r1) )
// Tile 32 o x 64 e; y1 read via LDS transpose; y2/out nontemporal.
// ---------------------------------------------------------------------------
__global__ __launch_bounds__(256) void final_k(
    const float* __restrict__ y2, const float* __restrict__ y1,
    const float2* __restrict__ st1, const float2* __restrict__ st2,
    float* __restrict__ out, int E)
{
  __shared__ float tile[32][65];
  const int b  = blockIdx.z;
  const int o0 = blockIdx.y * 32;
  const int e0 = blockIdx.x * 64;
  const int t  = threadIdx.x;

  // phase 1: load y1 [64e][32ch slice], normalize+relu, write transposed
  {
    const int e_l  = t >> 2;        // 0..63
    const int part = t & 3;         // 0..3  -> 8 channels each
    const int eg   = e0 + e_l;
    if (eg < E) {
      const float* src = y1 + ((size_t)b * E + eg) * 128 + o0 + part * 8;
      const f32x4 v0 = __builtin_nontemporal_load((const f32x4*)src);
      const f32x4 v1 = __builtin_nontemporal_load((const f32x4*)(src + 4));
      #pragma unroll
      for (int i = 0; i < 8; i++) {
        const float2 s1 = st1[b * 128 + o0 + part * 8 + i];
        float x = ((i < 4 ? v0[i] : v1[i - 4]) - s1.x) * s1.y;
        tile[part * 8 + i][e_l] = x < 0.f ? 0.f : x;
      }
    }
  }
  __syncthreads();

  // phase 2: y2 + residual, relu, store
  {
    const int col = t & 63;
    const int r   = t >> 6;
    const int eg  = e0 + col;
    if (eg < E) {
      #pragma unroll
      for (int k = 0; k < 8; k++) {
        const int o = o0 + r * 8 + k;
        const float2 s2 = st2[b * 128 + o];
        const size_t idx = ((size_t)b * 128 + o) * E + eg;
        float v = (__builtin_nontemporal_load(y2 + idx) - s2.x) * s2.y
                  + tile[r * 8 + k][col];
        v = v < 0.f ? 0.f : v;
        __builtin_nontemporal_store(v, out + idx);
      }
    }
  }
}

// ---------------------------------------------------------------------------
extern "C" void kernel_launch(void* const* d_in, const int* in_sizes, int n_in,
                              void* d_out, int out_size, void* d_ws, size_t ws_size,
                              hipStream_t stream)
{
  const float* fe  = (const float*)d_in[0];
  const int*   gmm = (const int*)d_in[1];
  const float* w1  = (const float*)d_in[2];
  const float* b1  = (const float*)d_in[3];
  const float* w2  = (const float*)d_in[4];
  const float* b2  = (const float*)d_in[5];
  float* out = (float*)d_out;

  const int B = 2, CIN = 64, COUT = 128;
  const int E = in_sizes[0] / (B * CIN);   // 100000
  const int nbx1 = (E + 63) / 64;          // conv1: EPB=64
  const int nbx2 = (E + 31) / 32;          // conv2: EPB=32

  // workspace layout: regA = feT (bf16, dead after conv1) aliased with y2
  char* p = (char*)d_ws;
  auto alloc = [&](size_t bytes) -> char* {
    char* q = p; p += (bytes + 255) & ~(size_t)255; return q;
  };
  const size_t feT_b = (size_t)B * E * CIN * 2;        // 25.6 MB
  const size_t y2_b  = (size_t)B * COUT * E * 4;       // 102.4 MB
  char* regA = alloc(y2_b > feT_b ? y2_b : feT_b);
  u16*   feT = (u16*)regA;
  float* y2  = (float*)regA;
  float* y1  = (float*)alloc((size_t)B * E * COUT * 4);   // 102.4 MB, persists
  float2* stats1 = (float2*)alloc((size_t)B * COUT * sizeof(float2));
  float2* stats2 = (float2*)alloc((size_t)B * COUT * sizeof(float2));
  u16* w1b = (u16*)alloc((size_t)COUT * CIN * 5 * 2);
  u16* w2b = (u16*)alloc((size_t)COUT * COUT * 5 * 2);
  // partials scratch in d_out: dead before final_k writes out
  float2* partials = (float2*)d_out;   // <= 256*nbx2*8B = 6.4 MB << out_size

  const int n_w1 = COUT * CIN * 5, n_w2 = COUT * COUT * 5;
  prep_w <<<dim3((n_w1 + 255) / 256), 256, 0, stream>>>(w1, w1b, COUT, CIN);
  prep_w <<<dim3((n_w2 + 255) / 256), 256, 0, stream>>>(w2, w2b, COUT, COUT);

  transpose64 <<<dim3((E + 63) / 64, 1, B), 256, 0, stream>>>(fe, feT, E);
  conv1_mfma <<<dim3(nbx1, 1, B), 512, 0, stream>>>(feT, gmm, w1b, b1, y1, partials, E, nbx1);
  stats_finalize <<<dim3(B * COUT), 256, 0, stream>>>(partials, stats1, nbx1, E);
  conv2_mfma <<<dim3(nbx2, 1, B), 512, 0, stream>>>(y1, gmm, w2b, b2, stats1, y2, partials, E, nbx2);
  stats_finalize <<<dim3(B * COUT), 256, 0, stream>>>(partials, stats2, nbx2, E);
  final_k <<<dim3((E + 63) / 64, COUT / 32, B), 256, 0, stream>>>(y2, y1, stats1, stats2, out, E);
}